// Round 11
// baseline (644.854 us; speedup 1.0000x reference)
//
#include <hip/hip_runtime.h>
#include <hip/hip_bf16.h>

// ---------------------------------------------------------------------------
// HybridGATLSTM on MI355X — round 17.
//   r16: all deltas neutral; total-fused gap (~165us) is fixed harness
//   overhead. The lever is the LSTM tail: 96 serial steps x ~2400cyc of
//   VALU GEMV. Round 17 replaces the 16 per-batch VALU rec blocks with ONE
//   MFMA mega-rec block per layer: the recurrence batched over 16 sequences
//   is a 16x512x128 GEMM (M=16 = batch fills mfma_f32_16x16x32 rows).
//     blocks 0..15 : L0 proj per batch (r15 proj, mega Pre layout, per-mt flag)
//     block  16    : mega-rec L0 (Whh frags resident, 48 MFMA/wave/step)
//     blocks 17..32: L1 proj per batch (r15 verbatim + mega Pre ring layout)
//     block  33    : mega-rec L1
//     blocks 34..49: L2 proj per batch
//     block  50    : mega-rec L2
//     blocks 51..  : GAT (r11 verbatim)
//   Handoffs copy r15's proven protocols hop-for-hop (plain stores + barrier
//   drain + threadfence + flag; consumers: flag spin + fence; h via atomic
//   loads). launch_bounds(512,1): VGPR cap 256 (mega-rec ~220); 1 block/CU.
//   NUMERICS: recurrence dot is now 3-term split-fp16 (same scheme as proj)
//   -> absmax moves for the first time; predicted ~1.2-1.5e-4.
//   Heads: r15's two kernels verbatim.
// ---------------------------------------------------------------------------

typedef _Float16 half8 __attribute__((ext_vector_type(8)));
typedef float floatx4 __attribute__((ext_vector_type(4)));
typedef float float4v __attribute__((ext_vector_type(4)));

#define LOG2E 1.44269504088896f

__device__ __forceinline__ float fast_exp(float x) {
    return __builtin_amdgcn_exp2f(x * LOG2E);
}
__device__ __forceinline__ float sigm(float x) {
    x = fminf(fmaxf(x, -30.f), 30.f);
    return __builtin_amdgcn_rcpf(1.f + __builtin_amdgcn_exp2f(-x * LOG2E));
}
__device__ __forceinline__ float tanhp(float x) {
    x = fminf(fmaxf(x, -15.f), 15.f);
    float e = __builtin_amdgcn_exp2f(-2.f * LOG2E * x);
    return (1.f - e) * __builtin_amdgcn_rcpf(1.f + e);
}
__device__ __forceinline__ void split8v(float4v v0, float4v v1, half8& hi, half8& lo) {
#pragma unroll
    for (int j = 0; j < 4; ++j) {
        _Float16 h = (_Float16)v0[j];
        hi[j] = h; lo[j] = (_Float16)(v0[j] - (float)h);
    }
#pragma unroll
    for (int j = 0; j < 4; ++j) {
        _Float16 h = (_Float16)v1[j];
        hi[4 + j] = h; lo[4 + j] = (_Float16)(v1[j] - (float)h);
    }
}

// ---------------------------------------------------------------------------
// Shared memory (union'd).
// MegaSh: gates [512][20pad] (40KB, 2-way banks) + h [16][132pad] (8.4KB).
// ---------------------------------------------------------------------------
struct __align__(16) MegaSh {
    float g[512 * 20];
    float h[16 * 132];
};
struct __align__(16) ProjSh {
    float stage[16 * 132];
};
struct __align__(16) GatSh {
    unsigned long long adjm[256];
    float xv[128];
    float u1[32], v1[32], coef[4];
    float s1v[128];
    float h2s[128 * 33];
    float wh2[128 * 17];
    float Lv[128], Rv[128], rd2[128];
    float d_h[4][128], s_h[4][128];
};
union ShU { MegaSh m; ProjSh p; GatSh gt; };

// ---------------------------------------------------------------------------
// L0 proj: one block per batch. r15 l0 proj with mega Pre layout
// PreM0[t][col][batch] and a per-mt flag (fast mega-rec start).
// ---------------------------------------------------------------------------
__device__ __forceinline__ void l0proj_body(int b,
    const float* __restrict__ x, const float* __restrict__ Wih,
    const float* __restrict__ bih, const float* __restrict__ bhh,
    float* __restrict__ PreM0, int* __restrict__ fL0)
{
    int tid = threadIdx.x;
    int w = tid >> 6, lane = tid & 63, quad = lane >> 4, sub = lane & 15;

    __builtin_amdgcn_s_setprio(1);
    half8 bhi[4][4], blo[4][4];
    float bias[4];
#pragma unroll
    for (int tt = 0; tt < 4; ++tt) {
        int r = tt * 128 + 16 * w + sub;
        bias[tt] = bih[r] + bhh[r];
#pragma unroll
        for (int kc = 0; kc < 4; ++kc) {
            const float4v* p = (const float4v*)(Wih + r * 128 + kc * 32 + quad * 8);
            split8v(p[0], p[1], bhi[tt][kc], blo[tt][kc]);
        }
    }
    for (int mt = 0; mt < 6; ++mt) {
        half8 ahi[4], alo[4];
        const float* arow = x + b * 12288 + (mt * 16 + sub) * 128;
#pragma unroll
        for (int kc = 0; kc < 4; ++kc) {
            const float4v* p = (const float4v*)(arow + kc * 32 + quad * 8);
            split8v(p[0], p[1], ahi[kc], alo[kc]);
        }
        floatx4 acc[4];
#pragma unroll
        for (int tt = 0; tt < 4; ++tt) {
            floatx4 a = {bias[tt], bias[tt], bias[tt], bias[tt]};
            acc[tt] = a;
        }
#pragma unroll
        for (int tt = 0; tt < 4; ++tt)
#pragma unroll
            for (int kc = 0; kc < 4; ++kc) {
                acc[tt] = __builtin_amdgcn_mfma_f32_16x16x32_f16(ahi[kc], bhi[tt][kc], acc[tt], 0, 0, 0);
                acc[tt] = __builtin_amdgcn_mfma_f32_16x16x32_f16(ahi[kc], blo[tt][kc], acc[tt], 0, 0, 0);
                acc[tt] = __builtin_amdgcn_mfma_f32_16x16x32_f16(alo[kc], bhi[tt][kc], acc[tt], 0, 0, 0);
            }
        // mega layout: PreM0[(t*512 + col)*16 + b], t = mt*16+quad*4+reg
#pragma unroll
        for (int tt = 0; tt < 4; ++tt) {
            int r2 = tt * 128 + 16 * w + sub;
#pragma unroll
            for (int reg = 0; reg < 4; ++reg)
                PreM0[(((mt * 16 + quad * 4 + reg) * 512) + r2) * 16 + b] = acc[tt][reg];
        }
        __syncthreads();   // drains every thread's stores (vmcnt0 at barrier)
        if (tid == 0) {
            __threadfence();
            atomicExch(&fL0[b * 8 + mt], 1);
        }
    }
    __builtin_amdgcn_s_setprio(0);
}

// ---------------------------------------------------------------------------
// Proj block (layers 1,2), one per batch: r15 verbatim except Pre ring uses
// mega layout [slot][tl][col][batch] and a per-batch chunk flag.
// ---------------------------------------------------------------------------
__device__ __forceinline__ void proj_body(ProjSh& sh, int layer, int b,
    const float* __restrict__ Wih, const float* __restrict__ bih,
    const float* __restrict__ bhh,
    const float* __restrict__ Hin, int* __restrict__ fH,
    float* __restrict__ PreRing, int* __restrict__ fP,
    int* __restrict__ cons)
{
    int tid = threadIdx.x;
    int w = tid >> 6, lane = tid & 63, quad = lane >> 4, sub = lane & 15;
    const float* WihL = Wih + layer * 65536;

    __builtin_amdgcn_s_setprio(1);
    half8 bhi[4][4], blo[4][4];
    float bias[4];
#pragma unroll
    for (int tt = 0; tt < 4; ++tt) {
        int r = tt * 128 + 16 * w + sub;
        bias[tt] = bih[layer * 512 + r] + bhh[layer * 512 + r];
#pragma unroll
        for (int kc = 0; kc < 4; ++kc) {
            const float4v* p = (const float4v*)(WihL + r * 128 + kc * 32 + quad * 8);
            split8v(p[0], p[1], bhi[tt][kc], blo[tt][kc]);
        }
    }
    for (int k = 0; k < 6; ++k) {
        if (tid == 0) {
            while (atomicAdd(&fH[k], 0) == 0) __builtin_amdgcn_s_sleep(2);
        }
        __syncthreads();
        // h chunk: atomic loads fetch from the coherence point (r15 pattern)
        {
            const float* inp = Hin + k * 2048;
#pragma unroll
            for (int u = 0; u < 4; ++u) {
                int e = tid * 4 + u;
                sh.stage[(e >> 7) * 132 + (e & 127)] =
                    atomicAdd((float*)&inp[e], 0.f);
            }
        }
        __syncthreads();
        half8 ahi[4], alo[4];
        const float* arow = &sh.stage[sub * 132];
#pragma unroll
        for (int kc = 0; kc < 4; ++kc) {
            const float4v* p = (const float4v*)(arow + kc * 32 + quad * 8);
            split8v(p[0], p[1], ahi[kc], alo[kc]);
        }
        floatx4 acc[4];
#pragma unroll
        for (int tt = 0; tt < 4; ++tt) {
            floatx4 a = {bias[tt], bias[tt], bias[tt], bias[tt]};
            acc[tt] = a;
        }
#pragma unroll
        for (int tt = 0; tt < 4; ++tt)
#pragma unroll
            for (int kc = 0; kc < 4; ++kc) {
                acc[tt] = __builtin_amdgcn_mfma_f32_16x16x32_f16(ahi[kc], bhi[tt][kc], acc[tt], 0, 0, 0);
                acc[tt] = __builtin_amdgcn_mfma_f32_16x16x32_f16(ahi[kc], blo[tt][kc], acc[tt], 0, 0, 0);
                acc[tt] = __builtin_amdgcn_mfma_f32_16x16x32_f16(alo[kc], bhi[tt][kc], acc[tt], 0, 0, 0);
            }
        if (k >= 3) {   // ring WAR: slot reusable once mega-rec did chunk k-3
            if (tid == 0) {
                while (atomicAdd(cons, 0) < k - 2) __builtin_amdgcn_s_sleep(2);
            }
            __syncthreads();
        }
        float* dst = PreRing + (k % 3) * 131072;
#pragma unroll
        for (int tt = 0; tt < 4; ++tt) {
            int r2 = tt * 128 + 16 * w + sub;
#pragma unroll
            for (int reg = 0; reg < 4; ++reg)
                dst[(((quad * 4 + reg) * 512) + r2) * 16 + b] = acc[tt][reg];
        }
        __syncthreads();
        if (tid == 0) {
            __threadfence();
            atomicExch(&fP[k * 16 + b], 1);
        }
    }
    __builtin_amdgcn_s_setprio(0);
}

// ---------------------------------------------------------------------------
// Mega-rec block (one per layer): recurrence for ALL 16 batches via MFMA.
// Wave w owns gate cols [64w, 64w+64) as 4 n-tiles. Whh split-fp16 B-frags
// resident (128 VGPR). Per step: acc init from Pre (prefetched) -> A-frags
// from LDS h (rows = batches, proven fragment pattern) -> 48 MFMA -> gates
// to LDS -> each thread activates 4 cells of one batch -> h to LDS + global.
// ---------------------------------------------------------------------------
__device__ __forceinline__ void megarec_body(MegaSh& sh, int layer,
    const float* __restrict__ WhhL,   // layer base
    const float* __restrict__ PreSrc, // L0: [96*512*16]; L1/2: ring [3][16*512*16]
    int* __restrict__ fPre,           // L0: b*8+mt flags; L1/2: k*16+b flags
    int* __restrict__ cons,           // L1/2: consumption counter (nullptr L0)
    float* __restrict__ Hout,         // layers 0,1: [16][96][128]
    int* __restrict__ fHout,          // layers 0,1: 6 chunk flags
    float* __restrict__ xl_out)       // layer 2: [16][128]
{
    int tid = threadIdx.x;
    int w = tid >> 6, lane = tid & 63, quad = lane >> 4, sub = lane & 15;
    int bb = tid >> 5, u0 = (tid & 31) * 4;   // act: batch bb, cells u0..u0+3

    __builtin_amdgcn_s_setprio(1);
    // resident Whh B-frags: rows rB = w*64 + nt*16 + sub
    half8 bhi[4][4], blo[4][4];
#pragma unroll
    for (int nt = 0; nt < 4; ++nt) {
        int rB = w * 64 + nt * 16 + sub;
#pragma unroll
        for (int kc = 0; kc < 4; ++kc) {
            const float4v* p = (const float4v*)(WhhL + rB * 128 + kc * 32 + quad * 8);
            split8v(p[0], p[1], bhi[nt][kc], blo[nt][kc]);
        }
    }
    {
        float4v z = {0.f, 0.f, 0.f, 0.f};
        *(float4v*)&sh.h[bb * 132 + u0] = z;
    }
    float cvar[4] = {0.f, 0.f, 0.f, 0.f};
    __syncthreads();

    float4v pren[4];
    for (int k = 0; k < 6; ++k) {
        if (tid == 0) {
            if (layer == 0) {
                for (int b2 = 0; b2 < 16; ++b2)
                    while (atomicAdd(&fPre[b2 * 8 + k], 0) == 0) __builtin_amdgcn_s_sleep(2);
            } else {
                for (int b2 = 0; b2 < 16; ++b2)
                    while (atomicAdd(&fPre[k * 16 + b2], 0) == 0) __builtin_amdgcn_s_sleep(2);
            }
            __threadfence();   // acquire (ring slot reuse / remote stores)
        }
        __syncthreads();
        const float* PreC = (layer == 0) ? PreSrc + k * (16 * 8192)
                                         : PreSrc + (k % 3) * 131072;
        for (int tl = 0; tl < 16; ++tl) {
            int t = k * 16 + tl;
            float4v acc[4];
            if (tl == 0) {
#pragma unroll
                for (int nt = 0; nt < 4; ++nt)
                    acc[nt] = *(const float4v*)(PreC + ((0 * 512) + (w * 64 + nt * 16 + sub)) * 16 + quad * 4);
            } else {
#pragma unroll
                for (int nt = 0; nt < 4; ++nt) acc[nt] = pren[nt];
            }
            if (tl < 15) {   // prefetch next step's Pre (covered by chunk flag)
#pragma unroll
                for (int nt = 0; nt < 4; ++nt)
                    pren[nt] = *(const float4v*)(PreC + (((tl + 1) * 512) + (w * 64 + nt * 16 + sub)) * 16 + quad * 4);
            }
            // A-frags from own h: rows = batches (sub), proven pattern
            half8 ahi[4], alo[4];
#pragma unroll
            for (int kc = 0; kc < 4; ++kc) {
                const float4v* p = (const float4v*)(&sh.h[sub * 132 + kc * 32 + quad * 8]);
                split8v(p[0], p[1], ahi[kc], alo[kc]);
            }
#pragma unroll
            for (int kc = 0; kc < 4; ++kc)
#pragma unroll
                for (int nt = 0; nt < 4; ++nt) {
                    acc[nt] = __builtin_amdgcn_mfma_f32_16x16x32_f16(ahi[kc], bhi[nt][kc], acc[nt], 0, 0, 0);
                    acc[nt] = __builtin_amdgcn_mfma_f32_16x16x32_f16(ahi[kc], blo[nt][kc], acc[nt], 0, 0, 0);
                    acc[nt] = __builtin_amdgcn_mfma_f32_16x16x32_f16(alo[kc], bhi[nt][kc], acc[nt], 0, 0, 0);
                }
            // gates -> LDS [col][20pad]: batches quad*4..+3 contiguous
#pragma unroll
            for (int nt = 0; nt < 4; ++nt)
                *(float4v*)&sh.g[(w * 64 + nt * 16 + sub) * 20 + quad * 4] = acc[nt];
            __syncthreads();
            // activations: 4 cells of batch bb
            float hr[4];
#pragma unroll
            for (int j = 0; j < 4; ++j) {
                int u = u0 + j;
                float gi = sh.g[u * 20 + bb];
                float gf = sh.g[(128 + u) * 20 + bb];
                float gg = sh.g[(256 + u) * 20 + bb];
                float go = sh.g[(384 + u) * 20 + bb];
                float c = sigm(gf) * cvar[j] + sigm(gi) * tanhp(gg);
                cvar[j] = c;
                hr[j] = sigm(go) * tanhp(c);
            }
            float4v hv = {hr[0], hr[1], hr[2], hr[3]};
            *(float4v*)&sh.h[bb * 132 + u0] = hv;     // safe: post-barrier1
            if (layer < 2) {
                *(float4v*)(Hout + bb * 12288 + t * 128 + u0) = hv;
            } else if (t == 95) {
                *(float4v*)(xl_out + bb * 128 + u0) = hv;
            }
            __syncthreads();   // h visible; drains global h stores (vmcnt0)
        }
        if (tid == 0) {
            if (layer > 0) atomicExch(cons, k + 1);
            if (layer < 2) {
                __threadfence();
                atomicExch(&fHout[k], 1);
            }
        }
    }
    __builtin_amdgcn_s_setprio(0);
}

// ---------------------------------------------------------------------------
// GAT body: r11 VERBATIM.
// ---------------------------------------------------------------------------
__device__ __forceinline__ void gat_body(GatSh& s, int m,
    const float* __restrict__ x, const float* __restrict__ adj,
    const float* __restrict__ W_emb, const float* __restrict__ b_emb,
    const float* __restrict__ W1, const float* __restrict__ a1,
    const float* __restrict__ W2, const float* __restrict__ a2,
    float* __restrict__ attn_out, float* __restrict__ xg)
{
    int tid = threadIdx.x;

    if (tid < 128) s.xv[tid] = x[m * 128 + tid];
#pragma unroll
    for (int base = 0; base < 16384; base += 512) {
        int idx = base + tid;
        unsigned long long msk = __ballot(adj[idx] > 0.f);
        if ((tid & 63) == 0) s.adjm[idx >> 6] = msk;
    }
    if (tid < 32) {
        float su = 0.f, sv = 0.f;
        for (int kk = 0; kk < 32; ++kk) {
            float w1v = W1[kk * 32 + tid];
            su += W_emb[kk] * w1v;
            sv += b_emb[kk] * w1v;
        }
        s.u1[tid] = su; s.v1[tid] = sv;
    }
    __syncthreads();
    if (tid < 4) {
        const float* av = a1 + ((tid >= 2) ? 32 : 0);
        const float* uv = (tid & 1) ? s.v1 : s.u1;
        float sum = 0.f;
        for (int f = 0; f < 32; ++f) sum += uv[f] * av[f];
        s.coef[tid] = sum;
    }
    __syncthreads();
    float cL = s.coef[0], dL = s.coef[1], cR = s.coef[2], dR = s.coef[3];

    {
        int i = tid & 127, q = tid >> 7;
        unsigned int ms = (unsigned int)(s.adjm[(i << 1) | (q >> 1)] >> ((q & 1) * 32));
        float Li = s.xv[i] * cL + dL;
        float den = 0.f, wsum = 0.f;
        int j0 = q * 32;
#pragma unroll
        for (int jj = 0; jj < 32; ++jj) {
            if ((ms >> jj) & 1) {
                float xj = s.xv[j0 + jj];
                float e = Li + xj * cR + dR;
                e = e > 0.f ? e : 0.2f * e;
                float p = fast_exp(e);
                den += p; wsum += p * xj;
            }
        }
        s.d_h[q][i] = den; s.s_h[q][i] = wsum;
    }
    __syncthreads();
    if (tid < 128) {
        float den = 0.f, wsum = 0.f;
#pragma unroll
        for (int q = 0; q < 4; ++q) { den += s.d_h[q][tid]; wsum += s.s_h[q][tid]; }
        s.s1v[tid] = wsum / den;
    }
    __syncthreads();
#pragma unroll
    for (int e0 = 0; e0 < 4096; e0 += 512) {
        int e = e0 + tid;
        int i = e >> 5, f = e & 31;
        float v = s.s1v[i] * s.u1[f] + s.v1[f];
        s.h2s[i * 33 + f] = v > 0.f ? v : fast_exp(v) - 1.f;
    }
    __syncthreads();
    {
        int i = tid >> 2, g0 = (tid & 3) * 4;
        float accv[4] = {0.f, 0.f, 0.f, 0.f};
        for (int f = 0; f < 32; ++f) {
            float hv = s.h2s[i * 33 + f];
#pragma unroll
            for (int g = 0; g < 4; ++g) accv[g] += hv * W2[f * 16 + g0 + g];
        }
#pragma unroll
        for (int g = 0; g < 4; ++g) s.wh2[i * 17 + g0 + g] = accv[g];
    }
    __syncthreads();
    if (tid < 256) {
        int i = tid & 127, which = tid >> 7;
        const float* aa = a2 + which * 16;
        float sum = 0.f;
#pragma unroll
        for (int g = 0; g < 16; ++g) sum += s.wh2[i * 17 + g] * aa[g];
        (which ? s.Rv : s.Lv)[i] = sum;
    }
    __syncthreads();
    {
        int i = tid & 127, q = tid >> 7;
        unsigned int ms = (unsigned int)(s.adjm[(i << 1) | (q >> 1)] >> ((q & 1) * 32));
        float Li = s.Lv[i];
        float den = 0.f;
        int j0 = q * 32;
#pragma unroll
        for (int jj = 0; jj < 32; ++jj) {
            if ((ms >> jj) & 1) {
                float e = Li + s.Rv[j0 + jj];
                e = e > 0.f ? e : 0.2f * e;
                den += fast_exp(e);
            }
        }
        s.d_h[q][i] = den;
    }
    __syncthreads();
    if (tid < 128) {
        float den = 0.f;
#pragma unroll
        for (int q = 0; q < 4; ++q) den += s.d_h[q][tid];
        s.rd2[tid] = 1.0f / den;
    }
    __syncthreads();

    float* aout = attn_out + (size_t)m * 16384;
#pragma unroll
    for (int k = 0; k < 8; ++k) {
        int e0 = k * 2048 + tid * 4;
        int i = e0 >> 7, j0 = e0 & 127;
        unsigned int bits = (unsigned int)(s.adjm[(i << 1) | (j0 >> 6)] >> (j0 & 63)) & 0xFu;
        float Li = s.Lv[i], ri = s.rd2[i];
        float4v p;
#pragma unroll
        for (int u = 0; u < 4; ++u) {
            float pv = 0.f;
            if ((bits >> u) & 1) {
                float e = Li + s.Rv[j0 + u];
                e = e > 0.f ? e : 0.2f * e;
                pv = fast_exp(e) * ri;
            }
            p[u] = pv;
        }
        *(float4v*)(aout + e0) = p;
    }

    if (m % 96 == 95) {
        int b = m / 96;
        int i = tid >> 2, g0 = (tid & 3) * 4;
        unsigned long long mA = s.adjm[i << 1], mB = s.adjm[(i << 1) | 1];
        float Li = s.Lv[i], ri = s.rd2[i];
        float accv[4] = {0.f, 0.f, 0.f, 0.f};
        for (int j = 0; j < 128; ++j) {
            unsigned long long mm = (j < 64) ? mA : mB;
            if ((mm >> (j & 63)) & 1) {
                float e = Li + s.Rv[j];
                e = e > 0.f ? e : 0.2f * e;
                float p = fast_exp(e) * ri;
#pragma unroll
                for (int g = 0; g < 4; ++g) accv[g] += p * s.wh2[j * 17 + g0 + g];
            }
        }
#pragma unroll
        for (int g = 0; g < 4; ++g) xg[b * 2048 + i * 16 + g0 + g] = accv[g];
    }
}

// ---------------------------------------------------------------------------
// Fused kernel. Flag map (ints, in FLAGS):
//   fL0   = [0..127]    (b*8 + mt)
//   fP1   = [128..223]  (k*16 + b)     cons1 = [240]     fH0 = [248..253]
//   fP2   = [288..383]  (k*16 + b)     cons2 = [400]     fH1 = [408..413]
// ---------------------------------------------------------------------------
__global__ __launch_bounds__(512, 1) void fused_kernel(
    const float* __restrict__ x, const float* __restrict__ adj,
    const float* __restrict__ W_emb, const float* __restrict__ b_emb,
    const float* __restrict__ W1, const float* __restrict__ a1,
    const float* __restrict__ W2, const float* __restrict__ a2,
    const float* __restrict__ Wih, const float* __restrict__ Whh,
    const float* __restrict__ bih, const float* __restrict__ bhh,
    float* __restrict__ PreM0, float* __restrict__ Ring1, float* __restrict__ Ring2,
    float* __restrict__ H0, float* __restrict__ H1,
    int* __restrict__ flags, float* __restrict__ xl_out,
    float* __restrict__ attn_out, float* __restrict__ xg)
{
    __shared__ ShU sh;
    int bb = blockIdx.x;
    if (bb < 16) {
        l0proj_body(bb, x, Wih, bih, bhh, PreM0, flags + 0);
    } else if (bb == 16) {
        megarec_body(sh.m, 0, Whh, PreM0, flags + 0, nullptr,
                     H0, flags + 248, nullptr);
    } else if (bb < 33) {
        proj_body(sh.p, 1, bb - 17, Wih, bih, bhh,
                  H0 + (bb - 17) * 12288, flags + 248,
                  Ring1, flags + 128, flags + 240);
    } else if (bb == 33) {
        megarec_body(sh.m, 1, Whh + 65536, Ring1, flags + 128, flags + 240,
                     H1, flags + 408, nullptr);
    } else if (bb < 50) {
        proj_body(sh.p, 2, bb - 34, Wih, bih, bhh,
                  H1 + (bb - 34) * 12288, flags + 408,
                  Ring2, flags + 288, flags + 400);
    } else if (bb == 50) {
        megarec_body(sh.m, 2, Whh + 131072, Ring2, flags + 288, flags + 400,
                     nullptr, nullptr, xl_out);
    } else {
        gat_body(sh.gt, bb - 51, x, adj, W_emb, b_emb, W1, a1, W2, a2, attn_out, xg);
    }
}

// ---------------------------------------------------------------------------
// Heads (r15 verbatim, two kernels)
// ---------------------------------------------------------------------------
__global__ __launch_bounds__(256) void head_partial_kernel(
    const float* __restrict__ xl, const float* __restrict__ xg,
    const float* __restrict__ W1, float* __restrict__ hp)
{
    int k = blockIdx.x >> 4, chunk = blockIdx.x & 15;
    int d = threadIdx.x & 63, bg = threadIdx.x >> 6;
    float acc[4] = {0.f, 0.f, 0.f, 0.f};
    int c0 = chunk * 136;
    for (int cc = c0; cc < c0 + 136; ++cc) {
        float wv = W1[(k * 2176 + cc) * 64 + d];
#pragma unroll
        for (int u = 0; u < 4; ++u) {
            int b = bg * 4 + u;
            float cv = (cc < 128) ? xl[b * 128 + cc] : xg[b * 2048 + cc - 128];
            acc[u] += wv * cv;
        }
    }
#pragma unroll
    for (int u = 0; u < 4; ++u)
        hp[(((k * 16 + chunk) * 16) + bg * 4 + u) * 64 + d] = acc[u];
}

__global__ __launch_bounds__(256) void head_final_kernel(
    const float* __restrict__ hp, const float* __restrict__ b1,
    const float* __restrict__ W2, const float* __restrict__ b2,
    const float* __restrict__ W3d, const float* __restrict__ b3d,
    const float* __restrict__ W3r, const float* __restrict__ b3r,
    const float* __restrict__ W3v, const float* __restrict__ b3v,
    float* __restrict__ out)
{
    __shared__ float h1s[3 * 16 * 64];
    __shared__ float h2s[3 * 16 * 32];
    int tid = threadIdx.x;
    for (int o = tid; o < 3072; o += 256) {
        int k = o >> 10, rem = o & 1023, b = rem >> 6, d = rem & 63;
        float s = b1[k * 64 + d];
        for (int ch = 0; ch < 16; ++ch)
            s += hp[(((k * 16 + ch) * 16) + b) * 64 + d];
        h1s[o] = fmaxf(s, 0.f);
    }
    __syncthreads();
    for (int o = tid; o < 1536; o += 256) {
        int k = o >> 9, rem = o & 511, b = rem >> 5, e = rem & 31;
        float s = b2[k * 32 + e];
        for (int dd = 0; dd < 64; ++dd)
            s += h1s[(k * 16 + b) * 64 + dd] * W2[(k * 64 + dd) * 32 + e];
        h2s[o] = fmaxf(s, 0.f);
    }
    __syncthreads();
    if (tid < 64) {
        if (tid < 16) {
            int b = tid; float s = b3d[0];
            for (int e = 0; e < 32; ++e) s += h2s[b * 32 + e] * W3d[e];
            out[b] = s;
        } else if (tid < 32) {
            int b = tid - 16; float s = b3r[0];
            for (int e = 0; e < 32; ++e) s += h2s[(16 + b) * 32 + e] * W3r[e];
            out[16 + b] = s;
        } else {
            int b = (tid - 32) >> 1, j = tid & 1; float s = b3v[j];
            for (int e = 0; e < 32; ++e) s += h2s[(32 + b) * 32 + e] * W3v[e * 2 + j];
            out[32 + b * 2 + j] = s;
        }
    }
}

// ---------------------------------------------------------------------------
extern "C" void kernel_launch(void* const* d_in, const int* in_sizes, int n_in,
                              void* d_out, int out_size, void* d_ws, size_t ws_size,
                              hipStream_t stream)
{
    const float* x     = (const float*)d_in[0];
    const float* adj   = (const float*)d_in[1];
    const float* W_emb = (const float*)d_in[2];
    const float* b_emb = (const float*)d_in[3];
    const float* W1    = (const float*)d_in[4];
    const float* a1    = (const float*)d_in[5];
    const float* W2    = (const float*)d_in[6];
    const float* a2    = (const float*)d_in[7];
    const float* Wih   = (const float*)d_in[8];
    const float* Whh   = (const float*)d_in[9];
    const float* bih   = (const float*)d_in[10];
    const float* bhh   = (const float*)d_in[11];
    const float* hW1   = (const float*)d_in[12];
    const float* hb1   = (const float*)d_in[13];
    const float* hW2   = (const float*)d_in[14];
    const float* hb2   = (const float*)d_in[15];
    const float* W3d   = (const float*)d_in[16];
    const float* b3d   = (const float*)d_in[17];
    const float* W3r   = (const float*)d_in[18];
    const float* b3r   = (const float*)d_in[19];
    const float* W3v   = (const float*)d_in[20];
    const float* b3v   = (const float*)d_in[21];

    float* out = (float*)d_out;
    float* wsf = (float*)d_ws;
    float* XG    = wsf;                    // 32768
    float* XL    = wsf + 32768;            // 2048
    float* HP    = wsf + 34816;            // 49152 -> 83968
    int*   FLAGS = (int*)(wsf + 83968);    // 512 ints -> next @ 84480
    float* PREM0 = wsf + 84480;            // 96*512*16 = 786432 -> 870912
    float* RING1 = wsf + 870912;           // 3*16*512*16 = 393216 -> 1264128
    float* RING2 = wsf + 1264128;          // 393216 -> 1657344
    float* H0    = wsf + 1657344;          // 16*12288 = 196608 -> 1853952
    float* H1    = wsf + 1853952;          // 196608 -> 2050560 (~8.2 MB)

    hipMemsetAsync(FLAGS, 0, 512 * sizeof(int), stream);
    fused_kernel<<<1587, 512, 0, stream>>>(
        x, adj, W_emb, b_emb, W1, a1, W2, a2,
        Wih, Whh, bih, bhh, PREM0, RING1, RING2, H0, H1, FLAGS, XL, out + 64, XG);
    head_partial_kernel<<<48, 256, 0, stream>>>(XL, XG, hW1, HP);
    head_final_kernel<<<1, 256, 0, stream>>>(HP, hb1, hW2, hb2, W3d, b3d, W3r, b3r, W3v, b3v, out);
}